// Round 16
// baseline (682.478 us; speedup 1.0000x reference)
//
#include <hip/hip_runtime.h>

#define L_SEQ 2048
#define BATCH 16
#define DDIM  1024
#define MDIM  (L_SEQ * BATCH)   // 32768
#define NDIM  (3 * DDIM)        // 3072
#define KDIM  DDIM              // 1024
#define CH    (BATCH * DDIM)    // 16384
#define NSEG  32
#define SEGL  64                // L_SEQ / NSEG

typedef __attribute__((ext_vector_type(8))) short short8;
typedef __attribute__((ext_vector_type(4))) float f32x4;

static __device__ __forceinline__ unsigned short f2bf(float f) {
  unsigned int u = __builtin_bit_cast(unsigned int, f);
  unsigned int lsb = (u >> 16) & 1u;
  u += 0x7fffu + lsb;
  return (unsigned short)(u >> 16);
}
static __device__ __forceinline__ float bf2f(unsigned short s) {
  unsigned int u = ((unsigned int)s) << 16;
  return __builtin_bit_cast(float, u);
}

static __device__ __forceinline__ void gll16(const void* g, void* l) {
  __builtin_amdgcn_global_load_lds(
      (const __attribute__((address_space(1))) unsigned int*)g,
      (__attribute__((address_space(3))) unsigned int*)l, 16, 0, 0);
}

// ---- converter (W only; x conversion fused into GEMM staging) ------------

// Wb[n][k] = bf16( W[k][colmap(n)] ): regions {xt, f, r} -> contiguous col ranges
__global__ void k_convert_w(const float* __restrict__ w, unsigned short* __restrict__ wb) {
  int gid = blockIdx.x * 256 + threadIdx.x;   // 3072*1024 total
  int k = gid & (KDIM - 1);
  int n = gid >> 10;
  int col = (n < DDIM) ? 3 * n : (n < 2 * DDIM) ? 3 * (n - DDIM) + 1 : 3 * (n - 2 * DDIM) + 2;
  wb[gid] = f2bf(w[(size_t)k * NDIM + col]);
}

// ---- GEMM: R3-champion schedule + fused A fp32->bf16 reg-staging ---------
// 256x256, BK=32, 4 x 32KB LDS buffers, 8 waves (2x4), reg-pipelined.
// A is staged from fp32 x: 4 float4 loads issued at tile T for tile T+3,
// cvt+ds_write at tile T+1 (T14 split, ~1 tile = ~3000cyc slack). B stays
// gll16 (bf16 wb). LDS bytes written are IDENTICAL to the gll16 layout
// (unit u=tid at Sb+tid*16, unit 512+tid at Sb+8192+tid*16) so all ds_read
// addressing is unchanged (proven 0-conflict slot permutation).
// vmcnt FIFO per tile: enter {A(T+2):4, B(T+1):2}=6; +A(T+3):4 -> 10;
// vmcnt(6) retires A(T+2); cvt+write; MFMA(mh0); +B(T+2):2 -> 8; vmcnt(6)
// retires B(T+1); lgkmcnt(0) (ds_write visible across raw barrier); barrier.

#define MFMA1(I, J, A, B) \
  acc[I][J] = __builtin_amdgcn_mfma_f32_16x16x32_bf16(A, B, acc[I][J], 0, 0, 0);

#define MFMAQ(BASE, A0, A1, A2, A3, B0, B1, B2, B3)  \
  MFMA1(BASE + 0, 0, A0, B0) MFMA1(BASE + 0, 1, A0, B1) \
  MFMA1(BASE + 0, 2, A0, B2) MFMA1(BASE + 0, 3, A0, B3) \
  MFMA1(BASE + 1, 0, A1, B0) MFMA1(BASE + 1, 1, A1, B1) \
  MFMA1(BASE + 1, 2, A1, B2) MFMA1(BASE + 1, 3, A1, B3) \
  MFMA1(BASE + 2, 0, A2, B0) MFMA1(BASE + 2, 1, A2, B1) \
  MFMA1(BASE + 2, 2, A2, B2) MFMA1(BASE + 2, 3, A2, B3) \
  MFMA1(BASE + 3, 0, A3, B0) MFMA1(BASE + 3, 1, A3, B1) \
  MFMA1(BASE + 3, 2, A3, B2) MFMA1(BASE + 3, 3, A3, B3)

#define CVT_WRITE(W0, W1, W2, W3, DST) do {                                  \
  short8 _w0, _w1;                                                           \
  _w0[0] = (short)f2bf(W0.x); _w0[1] = (short)f2bf(W0.y);                    \
  _w0[2] = (short)f2bf(W0.z); _w0[3] = (short)f2bf(W0.w);                    \
  _w0[4] = (short)f2bf(W1.x); _w0[5] = (short)f2bf(W1.y);                    \
  _w0[6] = (short)f2bf(W1.z); _w0[7] = (short)f2bf(W1.w);                    \
  _w1[0] = (short)f2bf(W2.x); _w1[1] = (short)f2bf(W2.y);                    \
  _w1[2] = (short)f2bf(W2.z); _w1[3] = (short)f2bf(W2.w);                    \
  _w1[4] = (short)f2bf(W3.x); _w1[5] = (short)f2bf(W3.y);                    \
  _w1[6] = (short)f2bf(W3.z); _w1[7] = (short)f2bf(W3.w);                    \
  *(short8*)((DST) + awr0)        = _w0;                                     \
  *(short8*)((DST) + 8192 + awr0) = _w1;                                     \
} while (0)

// One K-tile (BK=32). W* = reg set holding A(T+2) fp32; I* = set for A(T+3).
#define TILE(J, X0, X1, X2, X3, Y0, Y1, Y2, Y3, W0, W1, W2, W3, I0, I1, I2, I3) do { \
  const char* Ab  = LDSc + (((J)) & 3) * 32768;                              \
  const char* AbN = LDSc + (((J) + 1) & 3) * 32768;                          \
  char* Sb = LDSc + (((J) + 2) & 3) * 32768;                                 \
  const int kbS = ((i * 4 + (J) + 2) & 31) * 64;                             \
  const int kfA = ((i * 4 + (J) + 3) & 31) * 128;                            \
  q0 = *(const short8*)(Ab + aRd + 4096);                                    \
  q1 = *(const short8*)(Ab + aRd + 5120);                                    \
  q2 = *(const short8*)(Ab + aRd + 6144);                                    \
  q3 = *(const short8*)(Ab + aRd + 7168);                                    \
  I0 = *(const float4*)(srcAf0 + kfA);                                       \
  I1 = *(const float4*)(srcAf0 + kfA + 16);                                  \
  I2 = *(const float4*)(srcAf1 + kfA);                                       \
  I3 = *(const float4*)(srcAf1 + kfA + 16);                                  \
  __builtin_amdgcn_sched_barrier(0);                                         \
  asm volatile("s_waitcnt vmcnt(6)" ::: "memory");                           \
  CVT_WRITE(W0, W1, W2, W3, Sb);                                             \
  __builtin_amdgcn_s_setprio(1);                                             \
  MFMAQ(0, p0, p1, p2, p3, X0, X1, X2, X3)                                   \
  __builtin_amdgcn_s_setprio(0);                                             \
  gll16(srcB0 + kbS, Sb + 16384 + dstOff);                                   \
  gll16(srcB1 + kbS, Sb + 24576 + dstOff);                                   \
  __builtin_amdgcn_sched_barrier(0);                                         \
  asm volatile("s_waitcnt vmcnt(6)" ::: "memory");                           \
  asm volatile("s_waitcnt lgkmcnt(0)" ::: "memory");                         \
  __builtin_amdgcn_s_barrier();                                              \
  __builtin_amdgcn_sched_barrier(0);                                         \
  p0 = *(const short8*)(AbN + aRd);                                          \
  p1 = *(const short8*)(AbN + aRd + 1024);                                   \
  p2 = *(const short8*)(AbN + aRd + 2048);                                   \
  p3 = *(const short8*)(AbN + aRd + 3072);                                   \
  Y0 = *(const short8*)(AbN + 16384 + bRd);                                  \
  Y1 = *(const short8*)(AbN + 16384 + bRd + 1024);                           \
  Y2 = *(const short8*)(AbN + 16384 + bRd + 2048);                           \
  Y3 = *(const short8*)(AbN + 16384 + bRd + 3072);                           \
  __builtin_amdgcn_s_setprio(1);                                             \
  MFMAQ(4, q0, q1, q2, q3, X0, X1, X2, X3)                                   \
  __builtin_amdgcn_s_setprio(0);                                             \
} while (0)

__global__ __launch_bounds__(512, 2) void k_gemm256(
    const float* __restrict__ xf,            // [M][K] fp32 (raw input x)
    const unsigned short* __restrict__ wb,   // [N][K] bf16
    const float* __restrict__ bias,          // [2d]
    unsigned short* __restrict__ xtb,        // [M][d] bf16
    unsigned short* __restrict__ fbuf,       // [M][d] bf16
    unsigned short* __restrict__ rbuf) {     // [M][d] bf16
  __shared__ char LDS[131072];   // 4 buffers x (A 16KB + B 16KB)
  char* LDSc = LDS;

  const int tid  = threadIdx.x;
  const int lane = tid & 63;
  const int wid  = tid >> 6;
  const int wr   = wid >> 2;     // 0..1
  const int wc   = wid & 3;      // 0..3

  // XCD-aware bijective swizzle: 1536 = 8 * 192
  int bid = blockIdx.x;
  int wg = (bid & 7) * 192 + (bid >> 3);
  int mt = wg / 12;
  int nt = wg - mt * 12;
  const int rowBase = mt * 256;
  const int colBase = nt * 256;

  // ds_read bases (chunk-permuted layout: pos = row*4 + (slot ^ ((row>>1)&3)))
  const int l15 = lane & 15;
  const int sl  = lane >> 4;
  const int ra0 = wr * 128 + l15;
  const int rb0 = wc * 64 + l15;
  const int aRd = ra0 * 64 + (sl ^ ((ra0 >> 1) & 3)) * 16;
  const int bRd = rb0 * 64 + (sl ^ ((rb0 >> 1) & 3)) * 16;

  // staging addressing (inverse permutation on source, linear LDS dest)
  const int p0i = tid, p1i = 512 + tid;
  const int r0 = p0i >> 2, r1 = p1i >> 2;
  const int s0 = (p0i & 3) ^ ((r0 >> 1) & 3);
  const int s1 = (p1i & 3) ^ ((r1 >> 1) & 3);
  // A from fp32 x: bf16 16B unit (row, slot) == fp32 32B at row*4096 + slot*32
  const char* srcAf0 = (const char*)xf + (size_t)(rowBase + r0) * 4096 + s0 * 32;
  const char* srcAf1 = (const char*)xf + (size_t)(rowBase + r1) * 4096 + s1 * 32;
  const char* srcB0 = (const char*)wb + (size_t)(colBase + r0) * 2048 + s0 * 16;
  const char* srcB1 = (const char*)wb + (size_t)(colBase + r1) * 2048 + s1 * 16;
  const int dstOff = wid * 1024;
  const int awr0 = tid * 16;     // ds_write bytes == gll16's HW write bytes

  f32x4 acc[8][4];
#pragma unroll
  for (int ii = 0; ii < 8; ++ii)
#pragma unroll
    for (int jj = 0; jj < 4; ++jj)
      acc[ii][jj] = (f32x4){0.f, 0.f, 0.f, 0.f};

  float4 fE0, fE1, fE2, fE3;   // A reg set (even-parity tiles)
  float4 fO0, fO1, fO2, fO3;   // A reg set (odd-parity tiles)

  // ---- prologue: A(0)->regs, A(1)->regs, B(0),B(1) gll16; write A(0),A(1);
  //      reload A(2); exit with FIFO {B(1):2, A(2):4} ----
  fE0 = *(const float4*)(srcAf0);
  fE1 = *(const float4*)(srcAf0 + 16);
  fE2 = *(const float4*)(srcAf1);
  fE3 = *(const float4*)(srcAf1 + 16);
  __builtin_amdgcn_sched_barrier(0);
  fO0 = *(const float4*)(srcAf0 + 128);
  fO1 = *(const float4*)(srcAf0 + 144);
  fO2 = *(const float4*)(srcAf1 + 128);
  fO3 = *(const float4*)(srcAf1 + 144);
  __builtin_amdgcn_sched_barrier(0);
  gll16(srcB0,      LDSc + 16384 + dstOff);
  gll16(srcB1,      LDSc + 24576 + dstOff);
  gll16(srcB0 + 64, LDSc + 32768 + 16384 + dstOff);
  gll16(srcB1 + 64, LDSc + 32768 + 24576 + dstOff);
  __builtin_amdgcn_sched_barrier(0);
  CVT_WRITE(fE0, fE1, fE2, fE3, LDSc);              // A(0) -> buf0 (compiler waits)
  __builtin_amdgcn_sched_barrier(0);
  fE0 = *(const float4*)(srcAf0 + 256);             // A(2) -> fE
  fE1 = *(const float4*)(srcAf0 + 272);
  fE2 = *(const float4*)(srcAf1 + 256);
  fE3 = *(const float4*)(srcAf1 + 272);
  __builtin_amdgcn_sched_barrier(0);
  CVT_WRITE(fO0, fO1, fO2, fO3, LDSc + 32768);      // A(1) -> buf1 (compiler waits)
  __builtin_amdgcn_sched_barrier(0);
  asm volatile("s_waitcnt vmcnt(6)" ::: "memory");  // B(0) landed; {B(1):2, A(2):4} left
  asm volatile("s_waitcnt lgkmcnt(0)" ::: "memory");
  __builtin_amdgcn_s_barrier();
  __builtin_amdgcn_sched_barrier(0);

  short8 p0, p1, p2, p3;   // A mh0 frags
  short8 q0, q1, q2, q3;   // A mh1 frags
  short8 e0, e1, e2, e3;   // B set (even tiles)
  short8 o0, o1, o2, o3;   // B set (odd tiles)

  // preload tile 0: mh0 A frags + B frags
  p0 = *(const short8*)(LDSc + aRd);
  p1 = *(const short8*)(LDSc + aRd + 1024);
  p2 = *(const short8*)(LDSc + aRd + 2048);
  p3 = *(const short8*)(LDSc + aRd + 3072);
  e0 = *(const short8*)(LDSc + 16384 + bRd);
  e1 = *(const short8*)(LDSc + 16384 + bRd + 1024);
  e2 = *(const short8*)(LDSc + 16384 + bRd + 2048);
  e3 = *(const short8*)(LDSc + 16384 + bRd + 3072);

  for (int i = 0; i < 8; ++i) {
    TILE(0, e0, e1, e2, e3, o0, o1, o2, o3, fE0, fE1, fE2, fE3, fO0, fO1, fO2, fO3);
    TILE(1, o0, o1, o2, o3, e0, e1, e2, e3, fO0, fO1, fO2, fO3, fE0, fE1, fE2, fE3);
    TILE(2, e0, e1, e2, e3, o0, o1, o2, o3, fE0, fE1, fE2, fE3, fO0, fO1, fO2, fO3);
    TILE(3, o0, o1, o2, o3, e0, e1, e2, e3, fO0, fO1, fO2, fO3, fE0, fE1, fE2, fE3);
  }
  asm volatile("s_waitcnt vmcnt(0)" ::: "memory");

  // epilogue: region 0 -> x_tilde (bf16), 1 -> forget, 2 -> reset
  const int region = colBase >> 10;
#pragma unroll
  for (int qm = 0; qm < 2; ++qm) {
#pragma unroll
    for (int m = 0; m < 4; ++m) {
      int grow = rowBase + wr * 128 + qm * 64 + m * 16 + ((lane >> 4) << 2);
#pragma unroll
      for (int n = 0; n < 4; ++n) {
        int gcol = colBase + wc * 64 + n * 16 + (lane & 15);
        f32x4 v = acc[qm * 4 + m][n];
        if (region == 0) {
#pragma unroll
          for (int j = 0; j < 4; ++j)
            xtb[(size_t)(grow + j) * DDIM + gcol] = f2bf(v[j]);
        } else {
          float bv = bias[gcol - DDIM];
          unsigned short* dst = (region == 1) ? fbuf : rbuf;
          int lcol = gcol - (region << 10);
#pragma unroll
          for (int j = 0; j < 4; ++j) {
            float sg = 1.0f / (1.0f + __expf(-(v[j] + bv)));
            dst[(size_t)(grow + j) * DDIM + lcol] = f2bf(sg);
          }
        }
      }
    }
  }
}

// ---- segmented scan (R5-exact versions — session-best non-GEMM) ----------
// pass 1: per (segment, channel-pair) affine state a = prod f, b = scan from 0

__global__ __launch_bounds__(256) void k_scan1(
    const unsigned short* __restrict__ fbuf,
    const unsigned short* __restrict__ xtb,
    float4* __restrict__ AB) {
  int chp = blockIdx.x * 256 + threadIdx.x;       // 0..8191 channel pairs
  int seg = blockIdx.y;
  size_t base = (size_t)seg * SEGL * CH + chp * 2;
  const unsigned int* fp = (const unsigned int*)(fbuf + base);
  const unsigned int* xp = (const unsigned int*)(xtb + base);
  float a0 = 1.f, a1 = 1.f, b0 = 0.f, b1 = 0.f;
#pragma unroll 8
  for (int s = 0; s < SEGL; ++s) {
    unsigned int fv = fp[(size_t)s * (CH / 2)];
    unsigned int xv = xp[(size_t)s * (CH / 2)];
    float f0 = bf2f((unsigned short)fv), f1 = bf2f((unsigned short)(fv >> 16));
    float x0 = bf2f((unsigned short)xv), x1 = bf2f((unsigned short)(xv >> 16));
    b0 = (b0 - x0) * f0 + x0;  a0 *= f0;
    b1 = (b1 - x1) * f1 + x1;  a1 *= f1;
  }
  AB[(size_t)seg * (CH / 2) + chp] = (float4){a0, b0, a1, b1};
}

// pass 2: scan 32 segment states per channel; emit per-segment c_in and c_last

__global__ __launch_bounds__(256) void k_scan2(
    const float* __restrict__ c0,
    const float4* __restrict__ AB,
    float* __restrict__ Cin,
    float* __restrict__ clast) {
  int chp = blockIdx.x * 256 + threadIdx.x;       // 0..8191
  float2 cc = ((const float2*)c0)[chp];
  float ca = cc.x, cb = cc.y;
#pragma unroll
  for (int s = 0; s < NSEG; ++s) {
    ((float2*)Cin)[(size_t)s * (CH / 2) + chp] = (float2){ca, cb};
    float4 ab = AB[(size_t)s * (CH / 2) + chp];
    ca = ca * ab.x + ab.y;
    cb = cb * ab.z + ab.w;
  }
  ((float2*)clast)[chp] = (float2){ca, cb};
}

// pass 3: recompute c within segment from c_in; emit h

__global__ __launch_bounds__(256) void k_scan3(
    const float* __restrict__ x,
    const unsigned short* __restrict__ fbuf,
    const unsigned short* __restrict__ xtb,
    const unsigned short* __restrict__ rbuf,
    const float* __restrict__ Cin,
    float* __restrict__ h) {
  int chp = blockIdx.x * 256 + threadIdx.x;
  int seg = blockIdx.y;
  float2 cc = ((const float2*)Cin)[(size_t)seg * (CH / 2) + chp];
  float ca = cc.x, cb = cc.y;
  size_t base = (size_t)seg * SEGL * CH + chp * 2;
  const unsigned int* fp = (const unsigned int*)(fbuf + base);
  const unsigned int* tp = (const unsigned int*)(xtb + base);
  const unsigned int* rp = (const unsigned int*)(rbuf + base);
  const float2* xp = (const float2*)(x + base);
  float2* hp = (float2*)(h + base);
#pragma unroll 4
  for (int s = 0; s < SEGL; ++s) {
    unsigned int fv = fp[(size_t)s * (CH / 2)];
    unsigned int tv = tp[(size_t)s * (CH / 2)];
    unsigned int rv = rp[(size_t)s * (CH / 2)];
    float2 xv = xp[(size_t)s * (CH / 2)];
    float f0 = bf2f((unsigned short)fv), f1 = bf2f((unsigned short)(fv >> 16));
    float t0 = bf2f((unsigned short)tv), t1 = bf2f((unsigned short)(tv >> 16));
    float r0 = bf2f((unsigned short)rv), r1 = bf2f((unsigned short)(rv >> 16));
    ca = (ca - t0) * f0 + t0;
    cb = (cb - t1) * f1 + t1;
    float e0 = __expf(-2.f * fabsf(ca));
    float e1 = __expf(-2.f * fabsf(cb));
    float g0 = copysignf((1.f - e0) / (1.f + e0), ca);
    float g1 = copysignf((1.f - e1) / (1.f + e1), cb);
    float h0 = (g0 - xv.x) * r0 + xv.x;
    float h1 = (g1 - xv.y) * r1 + xv.y;
    hp[(size_t)s * (CH / 2)] = (float2){h0, h1};
  }
}

// ---- launch --------------------------------------------------------------

extern "C" void kernel_launch(void* const* d_in, const int* in_sizes, int n_in,
                              void* d_out, int out_size, void* d_ws, size_t ws_size,
                              hipStream_t stream) {
  const float* x    = (const float*)d_in[0];
  const float* w    = (const float*)d_in[1];
  const float* bias = (const float*)d_in[2];
  const float* c0   = (const float*)d_in[3];
  float* out = (float*)d_out;
  char* ws = (char*)d_ws;

  unsigned short* wb   = (unsigned short*)(ws);
  float4*         AB   = (float4*)(ws);
  float*          Cin  = (float*)(ws + 4194304);
  unsigned short* xtb  = (unsigned short*)(ws + 6291456);
  unsigned short* fbuf = (unsigned short*)(ws + 73400320);
  unsigned short* rbuf = (unsigned short*)(ws + 140509184);

  k_convert_w<<<(NDIM * KDIM) / 256, 256, 0, stream>>>(w, wb);

  k_gemm256<<<1536, 512, 0, stream>>>(x, wb, bias, xtb, fbuf, rbuf);

  k_scan1<<<dim3(32, NSEG), 256, 0, stream>>>(fbuf, xtb, AB);
  k_scan2<<<32, 256, 0, stream>>>(c0, AB, Cin, out + (size_t)L_SEQ * CH);
  k_scan3<<<dim3(32, NSEG), 256, 0, stream>>>(x, fbuf, xtb, rbuf, Cin, out);
}

// Round 17
// 419.314 us; speedup vs baseline: 1.6276x; 1.6276x over previous
//
#include <hip/hip_runtime.h>

#define L_SEQ 2048
#define BATCH 16
#define DDIM  1024
#define MDIM  (L_SEQ * BATCH)   // 32768
#define NDIM  (3 * DDIM)        // 3072
#define KDIM  DDIM              // 1024
#define CH    (BATCH * DDIM)    // 16384
#define NSEG  32
#define SEGL  64                // L_SEQ / NSEG

typedef __attribute__((ext_vector_type(8))) short short8;
typedef __attribute__((ext_vector_type(4))) float f32x4;

static __device__ __forceinline__ unsigned short f2bf(float f) {
  unsigned int u = __builtin_bit_cast(unsigned int, f);
  unsigned int lsb = (u >> 16) & 1u;
  u += 0x7fffu + lsb;
  return (unsigned short)(u >> 16);
}
static __device__ __forceinline__ float bf2f(unsigned short s) {
  unsigned int u = ((unsigned int)s) << 16;
  return __builtin_bit_cast(float, u);
}

static __device__ __forceinline__ void gll16(const void* g, void* l) {
  __builtin_amdgcn_global_load_lds(
      (const __attribute__((address_space(1))) unsigned int*)g,
      (__attribute__((address_space(3))) unsigned int*)l, 16, 0, 0);
}

// ---- converters ----------------------------------------------------------

__global__ void k_convert_x(const float4* __restrict__ x, ushort4* __restrict__ xb, int n4) {
  int i = blockIdx.x * blockDim.x + threadIdx.x;
  int stride = gridDim.x * blockDim.x;
  for (; i < n4; i += stride) {
    float4 v = x[i];
    ushort4 o;
    o.x = f2bf(v.x); o.y = f2bf(v.y); o.z = f2bf(v.z); o.w = f2bf(v.w);
    xb[i] = o;
  }
}

// Wb[n][k] = bf16( W[k][colmap(n)] ): regions {xt, f, r} -> contiguous col ranges
__global__ void k_convert_w(const float* __restrict__ w, unsigned short* __restrict__ wb) {
  int gid = blockIdx.x * 256 + threadIdx.x;   // 3072*1024 total
  int k = gid & (KDIM - 1);
  int n = gid >> 10;
  int col = (n < DDIM) ? 3 * n : (n < 2 * DDIM) ? 3 * (n - DDIM) + 1 : 3 * (n - 2 * DDIM) + 2;
  wb[gid] = f2bf(w[(size_t)k * NDIM + col]);
}

// ---- GEMM (R3 champion, VERBATIM): 256x256, BK=32, 4-buf, reg-pipelined --
// Best measured across 10 structural variants + 2 fusion attempts (R2-R16):
// 244.7-252.3 us, MfmaUtil ~37-38%, 0 bank conflicts, VGPR 128.
// Wave grid 2x4 (wr=wid>>2, wc=wid&3).

#define MFMA1(I, J, A, B) \
  acc[I][J] = __builtin_amdgcn_mfma_f32_16x16x32_bf16(A, B, acc[I][J], 0, 0, 0);

#define MFMAQ(BASE, A0, A1, A2, A3, B0, B1, B2, B3)  \
  MFMA1(BASE + 0, 0, A0, B0) MFMA1(BASE + 0, 1, A0, B1) \
  MFMA1(BASE + 0, 2, A0, B2) MFMA1(BASE + 0, 3, A0, B3) \
  MFMA1(BASE + 1, 0, A1, B0) MFMA1(BASE + 1, 1, A1, B1) \
  MFMA1(BASE + 1, 2, A1, B2) MFMA1(BASE + 1, 3, A1, B3) \
  MFMA1(BASE + 2, 0, A2, B0) MFMA1(BASE + 2, 1, A2, B1) \
  MFMA1(BASE + 2, 2, A2, B2) MFMA1(BASE + 2, 3, A2, B3) \
  MFMA1(BASE + 3, 0, A3, B0) MFMA1(BASE + 3, 1, A3, B1) \
  MFMA1(BASE + 3, 2, A3, B2) MFMA1(BASE + 3, 3, A3, B3)

// One K-tile (BK=32). P0: read cur mh1 A-frags, stage A(+2), MFMA(mh0).
// P1: stage B(+2), fence (vmcnt(4)+barrier), read NEXT tile mh0+B, MFMA(mh1).
#define TILE(J, X0, X1, X2, X3, Y0, Y1, Y2, Y3) do {                         \
  const char* Ab  = LDSc + (((J)) & 3) * 32768;                              \
  const char* AbN = LDSc + (((J) + 1) & 3) * 32768;                          \
  char* Sb = LDSc + (((J) + 2) & 3) * 32768;                                 \
  const int kbS = ((i * 4 + (J) + 2) & 31) * 64;                             \
  q0 = *(const short8*)(Ab + aRd + 4096);                                    \
  q1 = *(const short8*)(Ab + aRd + 5120);                                    \
  q2 = *(const short8*)(Ab + aRd + 6144);                                    \
  q3 = *(const short8*)(Ab + aRd + 7168);                                    \
  gll16(srcA0 + kbS, Sb + dstOff);                                           \
  gll16(srcA1 + kbS, Sb + 8192 + dstOff);                                    \
  __builtin_amdgcn_s_setprio(1);                                             \
  MFMAQ(0, p0, p1, p2, p3, X0, X1, X2, X3)                                   \
  __builtin_amdgcn_s_setprio(0);                                             \
  gll16(srcB0 + kbS, Sb + 16384 + dstOff);                                   \
  gll16(srcB1 + kbS, Sb + 24576 + dstOff);                                   \
  __builtin_amdgcn_sched_barrier(0);                                         \
  asm volatile("s_waitcnt vmcnt(4)" ::: "memory");                           \
  __builtin_amdgcn_s_barrier();                                              \
  __builtin_amdgcn_sched_barrier(0);                                         \
  p0 = *(const short8*)(AbN + aRd);                                          \
  p1 = *(const short8*)(AbN + aRd + 1024);                                   \
  p2 = *(const short8*)(AbN + aRd + 2048);                                   \
  p3 = *(const short8*)(AbN + aRd + 3072);                                   \
  Y0 = *(const short8*)(AbN + 16384 + bRd);                                  \
  Y1 = *(const short8*)(AbN + 16384 + bRd + 1024);                           \
  Y2 = *(const short8*)(AbN + 16384 + bRd + 2048);                           \
  Y3 = *(const short8*)(AbN + 16384 + bRd + 3072);                           \
  __builtin_amdgcn_s_setprio(1);                                             \
  MFMAQ(4, q0, q1, q2, q3, X0, X1, X2, X3)                                   \
  __builtin_amdgcn_s_setprio(0);                                             \
} while (0)

__global__ __launch_bounds__(512, 2) void k_gemm256(
    const unsigned short* __restrict__ xb,   // [M][K] bf16
    const unsigned short* __restrict__ wb,   // [N][K] bf16
    const float* __restrict__ bias,          // [2d]
    unsigned short* __restrict__ xtb,        // [M][d] bf16
    unsigned short* __restrict__ fbuf,       // [M][d] bf16
    unsigned short* __restrict__ rbuf) {     // [M][d] bf16
  __shared__ char LDS[131072];   // 4 buffers x (A 16KB + B 16KB)
  char* LDSc = LDS;

  const int tid  = threadIdx.x;
  const int lane = tid & 63;
  const int wid  = tid >> 6;
  const int wr   = wid >> 2;     // 0..1
  const int wc   = wid & 3;      // 0..3

  // XCD-aware bijective swizzle: 1536 = 8 * 192
  int bid = blockIdx.x;
  int wg = (bid & 7) * 192 + (bid >> 3);
  int mt = wg / 12;
  int nt = wg - mt * 12;
  const int rowBase = mt * 256;
  const int colBase = nt * 256;

  // ds_read bases (chunk-permuted layout: pos = row*4 + (slot ^ ((row>>1)&3)))
  const int l15 = lane & 15;
  const int sl  = lane >> 4;
  const int ra0 = wr * 128 + l15;
  const int rb0 = wc * 64 + l15;
  const int aRd = ra0 * 64 + (sl ^ ((ra0 >> 1) & 3)) * 16;
  const int bRd = rb0 * 64 + (sl ^ ((rb0 >> 1) & 3)) * 16;

  // staging source bases (inverse permutation on global source, linear LDS dest)
  const int p0i = tid, p1i = 512 + tid;
  const int r0 = p0i >> 2, r1 = p1i >> 2;
  const int s0 = (p0i & 3) ^ ((r0 >> 1) & 3);
  const int s1 = (p1i & 3) ^ ((r1 >> 1) & 3);
  const char* srcA0 = (const char*)xb + (size_t)(rowBase + r0) * 2048 + s0 * 16;
  const char* srcA1 = (const char*)xb + (size_t)(rowBase + r1) * 2048 + s1 * 16;
  const char* srcB0 = (const char*)wb + (size_t)(colBase + r0) * 2048 + s0 * 16;
  const char* srcB1 = (const char*)wb + (size_t)(colBase + r1) * 2048 + s1 * 16;
  const int dstOff = wid * 1024;

  f32x4 acc[8][4];
#pragma unroll
  for (int ii = 0; ii < 8; ++ii)
#pragma unroll
    for (int jj = 0; jj < 4; ++jj)
      acc[ii][jj] = (f32x4){0.f, 0.f, 0.f, 0.f};

  // prologue: stage tiles 0 and 1
#pragma unroll
  for (int u = 0; u < 2; ++u) {
    char* ldsu = LDSc + u * 32768;
    gll16(srcA0 + u * 64, ldsu + dstOff);
    gll16(srcA1 + u * 64, ldsu + 8192 + dstOff);
    gll16(srcB0 + u * 64, ldsu + 16384 + dstOff);
    gll16(srcB1 + u * 64, ldsu + 24576 + dstOff);
  }
  asm volatile("s_waitcnt vmcnt(4)" ::: "memory");
  __builtin_amdgcn_s_barrier();
  __builtin_amdgcn_sched_barrier(0);

  short8 p0, p1, p2, p3;   // A mh0 frags
  short8 q0, q1, q2, q3;   // A mh1 frags
  short8 e0, e1, e2, e3;   // B set (even tiles)
  short8 o0, o1, o2, o3;   // B set (odd tiles)

  // preload tile 0: mh0 A frags + B frags
  p0 = *(const short8*)(LDSc + aRd);
  p1 = *(const short8*)(LDSc + aRd + 1024);
  p2 = *(const short8*)(LDSc + aRd + 2048);
  p3 = *(const short8*)(LDSc + aRd + 3072);
  e0 = *(const short8*)(LDSc + 16384 + bRd);
  e1 = *(const short8*)(LDSc + 16384 + bRd + 1024);
  e2 = *(const short8*)(LDSc + 16384 + bRd + 2048);
  e3 = *(const short8*)(LDSc + 16384 + bRd + 3072);

  for (int i = 0; i < 8; ++i) {
    TILE(0, e0, e1, e2, e3, o0, o1, o2, o3);
    TILE(1, o0, o1, o2, o3, e0, e1, e2, e3);
    TILE(2, e0, e1, e2, e3, o0, o1, o2, o3);
    TILE(3, o0, o1, o2, o3, e0, e1, e2, e3);
  }
  asm volatile("s_waitcnt vmcnt(0)" ::: "memory");

  // epilogue: region 0 -> x_tilde (bf16), 1 -> forget, 2 -> reset
  const int region = colBase >> 10;
#pragma unroll
  for (int qm = 0; qm < 2; ++qm) {
#pragma unroll
    for (int m = 0; m < 4; ++m) {
      int grow = rowBase + wr * 128 + qm * 64 + m * 16 + ((lane >> 4) << 2);
#pragma unroll
      for (int n = 0; n < 4; ++n) {
        int gcol = colBase + wc * 64 + n * 16 + (lane & 15);
        f32x4 v = acc[qm * 4 + m][n];
        if (region == 0) {
#pragma unroll
          for (int j = 0; j < 4; ++j)
            xtb[(size_t)(grow + j) * DDIM + gcol] = f2bf(v[j]);
        } else {
          float bv = bias[gcol - DDIM];
          unsigned short* dst = (region == 1) ? fbuf : rbuf;
          int lcol = gcol - (region << 10);
#pragma unroll
          for (int j = 0; j < 4; ++j) {
            float sg = 1.0f / (1.0f + __expf(-(v[j] + bv)));
            dst[(size_t)(grow + j) * DDIM + lcol] = f2bf(sg);
          }
        }
      }
    }
  }
}

// ---- segmented scan (R5-exact versions — session-best non-GEMM) ----------
// pass 1: per (segment, channel-pair) affine state a = prod f, b = scan from 0

__global__ __launch_bounds__(256) void k_scan1(
    const unsigned short* __restrict__ fbuf,
    const unsigned short* __restrict__ xtb,
    float4* __restrict__ AB) {
  int chp = blockIdx.x * 256 + threadIdx.x;       // 0..8191 channel pairs
  int seg = blockIdx.y;
  size_t base = (size_t)seg * SEGL * CH + chp * 2;
  const unsigned int* fp = (const unsigned int*)(fbuf + base);
  const unsigned int* xp = (const unsigned int*)(xtb + base);
  float a0 = 1.f, a1 = 1.f, b0 = 0.f, b1 = 0.f;
#pragma unroll 8
  for (int s = 0; s < SEGL; ++s) {
    unsigned int fv = fp[(size_t)s * (CH / 2)];
    unsigned int xv = xp[(size_t)s * (CH / 2)];
    float f0 = bf2f((unsigned short)fv), f1 = bf2f((unsigned short)(fv >> 16));
    float x0 = bf2f((unsigned short)xv), x1 = bf2f((unsigned short)(xv >> 16));
    b0 = (b0 - x0) * f0 + x0;  a0 *= f0;
    b1 = (b1 - x1) * f1 + x1;  a1 *= f1;
  }
  AB[(size_t)seg * (CH / 2) + chp] = (float4){a0, b0, a1, b1};
}

// pass 2: scan 32 segment states per channel; emit per-segment c_in and c_last

__global__ __launch_bounds__(256) void k_scan2(
    const float* __restrict__ c0,
    const float4* __restrict__ AB,
    float* __restrict__ Cin,
    float* __restrict__ clast) {
  int chp = blockIdx.x * 256 + threadIdx.x;       // 0..8191
  float2 cc = ((const float2*)c0)[chp];
  float ca = cc.x, cb = cc.y;
#pragma unroll
  for (int s = 0; s < NSEG; ++s) {
    ((float2*)Cin)[(size_t)s * (CH / 2) + chp] = (float2){ca, cb};
    float4 ab = AB[(size_t)s * (CH / 2) + chp];
    ca = ca * ab.x + ab.y;
    cb = cb * ab.z + ab.w;
  }
  ((float2*)clast)[chp] = (float2){ca, cb};
}

// pass 3: recompute c within segment from c_in; emit h

__global__ __launch_bounds__(256) void k_scan3(
    const float* __restrict__ x,
    const unsigned short* __restrict__ fbuf,
    const unsigned short* __restrict__ xtb,
    const unsigned short* __restrict__ rbuf,
    const float* __restrict__ Cin,
    float* __restrict__ h) {
  int chp = blockIdx.x * 256 + threadIdx.x;
  int seg = blockIdx.y;
  float2 cc = ((const float2*)Cin)[(size_t)seg * (CH / 2) + chp];
  float ca = cc.x, cb = cc.y;
  size_t base = (size_t)seg * SEGL * CH + chp * 2;
  const unsigned int* fp = (const unsigned int*)(fbuf + base);
  const unsigned int* tp = (const unsigned int*)(xtb + base);
  const unsigned int* rp = (const unsigned int*)(rbuf + base);
  const float2* xp = (const float2*)(x + base);
  float2* hp = (float2*)(h + base);
#pragma unroll 4
  for (int s = 0; s < SEGL; ++s) {
    unsigned int fv = fp[(size_t)s * (CH / 2)];
    unsigned int tv = tp[(size_t)s * (CH / 2)];
    unsigned int rv = rp[(size_t)s * (CH / 2)];
    float2 xv = xp[(size_t)s * (CH / 2)];
    float f0 = bf2f((unsigned short)fv), f1 = bf2f((unsigned short)(fv >> 16));
    float t0 = bf2f((unsigned short)tv), t1 = bf2f((unsigned short)(tv >> 16));
    float r0 = bf2f((unsigned short)rv), r1 = bf2f((unsigned short)(rv >> 16));
    ca = (ca - t0) * f0 + t0;
    cb = (cb - t1) * f1 + t1;
    float e0 = __expf(-2.f * fabsf(ca));
    float e1 = __expf(-2.f * fabsf(cb));
    float g0 = copysignf((1.f - e0) / (1.f + e0), ca);
    float g1 = copysignf((1.f - e1) / (1.f + e1), cb);
    float h0 = (g0 - xv.x) * r0 + xv.x;
    float h1 = (g1 - xv.y) * r1 + xv.y;
    hp[(size_t)s * (CH / 2)] = (float2){h0, h1};
  }
}

// ---- launch --------------------------------------------------------------

extern "C" void kernel_launch(void* const* d_in, const int* in_sizes, int n_in,
                              void* d_out, int out_size, void* d_ws, size_t ws_size,
                              hipStream_t stream) {
  const float* x    = (const float*)d_in[0];
  const float* w    = (const float*)d_in[1];
  const float* bias = (const float*)d_in[2];
  const float* c0   = (const float*)d_in[3];
  float* out = (float*)d_out;
  char* ws = (char*)d_ws;

  unsigned short* wb   = (unsigned short*)(ws);
  float4*         AB   = (float4*)(ws);
  float*          Cin  = (float*)(ws + 4194304);
  unsigned short* xtb  = (unsigned short*)(ws + 6291456);
  unsigned short* fbuf = (unsigned short*)(ws + 73400320);
  unsigned short* rbuf = (unsigned short*)(ws + 140509184);
  unsigned short* xb = (unsigned short*)d_out;   // h-region, dead until scan3

  k_convert_x<<<2048, 256, 0, stream>>>((const float4*)x, (ushort4*)xb, MDIM * KDIM / 4);
  k_convert_w<<<(NDIM * KDIM) / 256, 256, 0, stream>>>(w, wb);

  k_gemm256<<<1536, 512, 0, stream>>>(xb, wb, bias, xtb, fbuf, rbuf);

  k_scan1<<<dim3(32, NSEG), 256, 0, stream>>>(fbuf, xtb, AB);
  k_scan2<<<32, 256, 0, stream>>>(c0, AB, Cin, out + (size_t)L_SEQ * CH);
  k_scan3<<<dim3(32, NSEG), 256, 0, stream>>>(x, fbuf, xtb, rbuf, Cin, out);
}